// Round 6
// baseline (147.810 us; speedup 1.0000x reference)
//
#include <hip/hip_runtime.h>

#define NN 4096
#define C 256
#define NH 4
#define CH 64
#define JSPLIT 16
#define JSLICE (NN / JSPLIT)     // 256
#define NJT (JSLICE / 32)        // 8

typedef float f32x4 __attribute__((ext_vector_type(4)));
typedef __bf16 b16x8 __attribute__((ext_vector_type(8)));
typedef unsigned short u16x8 __attribute__((ext_vector_type(8)));
typedef unsigned int u32x4 __attribute__((ext_vector_type(4)));
typedef _Float16 f16x2 __attribute__((ext_vector_type(2)));

__device__ inline float fast_exp2(float x) {
#if __has_builtin(__builtin_amdgcn_exp2f)
  return __builtin_amdgcn_exp2f(x);
#else
  return exp2f(x);
#endif
}

// pack two f32 -> (bf16(f0) | bf16(f1)<<16), round-half-up via +0x8000, v_perm pack
__device__ inline unsigned pack2bf(float f0, float f1) {
  unsigned u0 = __float_as_uint(f0) + 0x8000u;
  unsigned u1 = __float_as_uint(f1) + 0x8000u;
  return __builtin_amdgcn_perm(u1, u0, 0x07060302u);
}

// async global->LDS, 16B per lane; LDS dest is wave-uniform base + lane*16,
// global src is per-lane (guide m97/m104 pattern)
__device__ inline void stage1k(const unsigned short* g, unsigned short* l) {
  __builtin_amdgcn_global_load_lds(
      (const __attribute__((address_space(1))) void*)g,
      (__attribute__((address_space(3))) void*)l, 16, 0, 0);
}

// ---------------- Kernel 0: prep — X->bf16, W->bf16 transposed (small, ~2us)
__global__ __launch_bounds__(256) void k_prep(
    const float* __restrict__ X, const float* __restrict__ W,
    unsigned short* __restrict__ Xbf, unsigned short* __restrict__ WT) {
  const int b = blockIdx.x, t = threadIdx.x;
  if (b < 1024) {
    const int idx = b * 256 + t;
    const float4 v = ((const float4*)X)[idx];
    uint2 st;
    st.x = pack2bf(v.x, v.y);
    st.y = pack2bf(v.z, v.w);
    ((uint2*)Xbf)[idx] = st;
  } else {
    const int c = b - 1024;
    const float w = W[(size_t)t * C + c];
    WT[(size_t)c * C + t] = (unsigned short)((__float_as_uint(w) + 0x8000u) >> 16);
  }
}

// ---------------- Kernel 1: feats GEMM (blocks 0..255) MERGED with adj bit-packing
// (blocks 256..8447) so the 64MB adj stream overlaps the 255-idle-CU GEMM.
__global__ __launch_bounds__(256) void k_feats(
    const unsigned short* __restrict__ Xbf, const unsigned short* __restrict__ WT,
    const float* __restrict__ bias, const float* __restrict__ av,
    const int* __restrict__ adj, unsigned char* __restrict__ packed,
    unsigned short* __restrict__ F, float2* __restrict__ srcAB,
    float2* __restrict__ EdT2) {
  if (blockIdx.x >= 256) {
    const int idx = (blockIdx.x - 256) * 256 + threadIdx.x;
    const int4 a0 = *(const int4*)(adj + (size_t)idx * 8);
    const int4 a1 = *(const int4*)(adj + (size_t)idx * 8 + 4);
    unsigned m = 0;
    m |= (a0.x != 0) ? 1u : 0u;   m |= (a0.y != 0) ? 2u : 0u;
    m |= (a0.z != 0) ? 4u : 0u;   m |= (a0.w != 0) ? 8u : 0u;
    m |= (a1.x != 0) ? 16u : 0u;  m |= (a1.y != 0) ? 32u : 0u;
    m |= (a1.z != 0) ? 64u : 0u;  m |= (a1.w != 0) ? 128u : 0u;
    packed[idx] = (unsigned char)m;
    return;
  }
  const int i0 = blockIdx.x * 16;
  const int h = threadIdx.x >> 6;
  const int lane = threadIdx.x & 63;
  const int q = lane >> 4, n = lane & 15;
  const int c0 = h * CH;
  const float LOG2E = 1.4426950408889634f;

  const f32x4 zero = {0.f, 0.f, 0.f, 0.f};
  f32x4 acc[4];
#pragma unroll
  for (int g = 0; g < 4; ++g) acc[g] = zero;

  const unsigned short* ap = Xbf + (size_t)(i0 + n) * C + q * 8;
#pragma unroll
  for (int kt = 0; kt < 8; ++kt) {
    const b16x8 aF = __builtin_bit_cast(b16x8, *(const u16x8*)(ap + kt * 32));
#pragma unroll
    for (int g = 0; g < 4; ++g) {
      const b16x8 bF = __builtin_bit_cast(b16x8,
          *(const u16x8*)(WT + (size_t)(c0 + g * 16 + n) * C + kt * 32 + q * 8));
      acc[g] = __builtin_amdgcn_mfma_f32_16x16x32_bf16(aF, bF, acc[g], 0, 0, 0);
    }
  }

  float fb[4][4], asv[4], adv[4];
#pragma unroll
  for (int g = 0; g < 4; ++g) {
    const float bs = bias[c0 + g * 16 + n];
    asv[g] = av[h * 128 + g * 16 + n];
    adv[g] = av[h * 128 + 64 + g * 16 + n];
#pragma unroll
    for (int r = 0; r < 4; ++r) fb[g][r] = acc[g][r] + bs;
  }
  const int jt = i0 >> 5, half = (i0 >> 4) & 1;
  const int qp = half * 2 + (q >> 1);
#pragma unroll
  for (int g = 0; g < 4; ++g) {
    uint2 st;
    st.x = pack2bf(fb[g][0], fb[g][1]);
    st.y = pack2bf(fb[g][2], fb[g][3]);
    *(uint2*)(F + ((size_t)((jt * NH + h) * 4 + g)) * 512 + (qp * 16 + n) * 8 + 4 * (q & 1)) = st;
  }
  // factored softmax: e_ij = max(e^{d_j}*A_i, e^{.2d_j}*B_i); A,B row-stable-scaled
#pragma unroll
  for (int r = 0; r < 4; ++r) {
    float p = 0.f, d = 0.f;
#pragma unroll
    for (int g = 0; g < 4; ++g) {
      p = fmaf(fb[g][r], asv[g], p);
      d = fmaf(fb[g][r], adv[g], d);
    }
#pragma unroll
    for (int m = 1; m < 16; m <<= 1) {
      p += __shfl_xor(p, m);
      d += __shfl_xor(d, m);
    }
    if (n == 0) {
      const int row = i0 + q * 4 + r;
      const float dL = d * LOG2E;
      EdT2[(size_t)h * NN + row] = make_float2(fast_exp2(dL), fast_exp2(0.2f * dL));
      const float x = p + 16.0f;
      const float m2 = fmaxf(x, 0.2f * x) * LOG2E;
      srcAB[(size_t)row * NH + h] = make_float2(
          fast_exp2(fmaf(p, LOG2E, -m2)),
          fast_exp2(fmaf(0.2f * p, LOG2E, -m2)));
    }
  }
}

// ---------------- Kernel 2: masked-softmax attention + PV via MFMA
// 64 rows x 4 heads per block (8 waves, 512 thr); wave = 32 rows x 1 head.
// F tiles staged to LDS via global_load_lds (16KB/jt, double-buffered): the two
// row-group waves of a head SHARE one staged copy (halves F L2 traffic) and the
// async DMA + single barrier/jt hides the vmem latency that dominated at 52 VGPR.
// launch_bounds min-waves stays 4 (cap 128 VGPR): declaring 8 forced <=64 and
// spilled the 40-reg accumulators in round 4 (495MB scratch writes, 2.9x slower).
__global__ __launch_bounds__(512, 4) void k_attn(
    const unsigned char* __restrict__ packed,
    const unsigned short* __restrict__ F,
    const float2* __restrict__ srcAB, const float2* __restrict__ EdT2,
    _Float16* __restrict__ pacc, float* __restrict__ lpart) {
  __shared__ unsigned short smem[2][16 * 512];   // 2 x 16KB

  const int wgid = blockIdx.x;                   // 1024 blocks
  const int slice = (wgid & 7) | (((wgid >> 9) & 1) << 3);   // XCD-pinned slices
  const int i0 = ((wgid >> 3) & 63) * 64;
  const int tid = threadIdx.x;
  const int wv = tid >> 6;                       // 0..7
  const int h = wv & 3;
  const int rg = wv >> 2;                        // row group 0/1
  const int lane = tid & 63;
  const int q = lane >> 4, n = lane & 15;
  const int jbase = slice * JSLICE;
  const int ib = i0 + rg * 32;

  const int r0 = ib + n, r1 = ib + 16 + n;
  const float2 ab0 = srcAB[(size_t)r0 * NH + h];
  const float2 ab1 = srcAB[(size_t)r1 * NH + h];

  const f32x4 zero = {0.f, 0.f, 0.f, 0.f};
  f32x4 acc0[4], acc1[4], lacc0 = zero, lacc1 = zero;
#pragma unroll
  for (int g = 0; g < 4; ++g) { acc0[g] = zero; acc1[g] = zero; }

  u16x8 ou;
#pragma unroll
  for (int jj = 0; jj < 8; ++jj) ou[jj] = 0x3F80;
  const b16x8 ones = __builtin_bit_cast(b16x8, ou);

  // per-wave slice masks: lane (q,n) holds 8-byte chunk q of rows r0 / r1
  const uint2 m20 = *(const uint2*)(packed + (size_t)r0 * 512 + (jbase >> 3) + q * 8);
  const uint2 m21 = *(const uint2*)(packed + (size_t)r1 * 512 + (jbase >> 3) + q * 8);

  const float* dp2 = (const float*)(EdT2 + (size_t)h * NN + jbase);
  // F chunk index is linear: ((jt_g*NH+h)*4+g) = (jbase>>5)*16 + jt*16 + (h*4+g)
  const unsigned short* fpb = F + (size_t)(jbase >> 5) * (16 * 512);
  const int ch0 = wv * 2, ch1 = wv * 2 + 1;      // this wave's 2 staging chunks

  // prologue: stage jt=0 into buffer 0
  stage1k(fpb + (size_t)(0 * 16 + ch0) * 512 + lane * 8, &smem[0][ch0 * 512]);
  stage1k(fpb + (size_t)(0 * 16 + ch1) * 512 + lane * 8, &smem[0][ch1 * 512]);

#pragma unroll
  for (int jt = 0; jt < NJT; ++jt) {
    const int cur = jt & 1;
    __syncthreads();   // drains this wave's stage(jt) (implicit vmcnt(0)) + block sync
    if (jt + 1 < NJT) {   // async-prefetch next tile into the other buffer
      stage1k(fpb + (size_t)((jt + 1) * 16 + ch0) * 512 + lane * 8, &smem[cur ^ 1][ch0 * 512]);
      stage1k(fpb + (size_t)((jt + 1) * 16 + ch1) * 512 + lane * 8, &smem[cur ^ 1][ch1 * 512]);
    }

    // B fragments from LDS (shared by both row-group waves of this head)
    b16x8 bF[4];
#pragma unroll
    for (int g = 0; g < 4; ++g)
      bF[g] = __builtin_bit_cast(b16x8,
          *(const u16x8*)(&smem[cur][(h * 4 + g) * 512 + lane * 8]));

    // masks: byte (jt*4 + q) of row's slice-mask, via shfl from lane (jt>>1)*16+n
    const int a = jt >> 1, b = jt & 1;
    const int w0 = b ? (int)m20.y : (int)m20.x;
    const int w1 = b ? (int)m21.y : (int)m21.x;
    const unsigned Mb0 = (unsigned(__shfl(w0, a * 16 + n)) >> (q * 8)) & 0xffu;
    const unsigned Mb1 = (unsigned(__shfl(w1, a * 16 + n)) >> (q * 8)) & 0xffu;

    // exp pairs {e^d, e^{.2d}} for this lane's 8 j's (broadcast loads, L2-hit)
    const float* dq = dp2 + jt * 64 + q * 16;
    const float4 dd0 = *(const float4*)(dq);
    const float4 dd1 = *(const float4*)(dq + 4);
    const float4 dd2 = *(const float4*)(dq + 8);
    const float4 dd3 = *(const float4*)(dq + 12);
    const float4 dd[4] = {dd0, dd1, dd2, dd3};

    u32x4 pk0, pk1;
#pragma unroll
    for (int k = 0; k < 4; ++k) {
      const float4 d = dd[k];
      const float e00 = (Mb0 & (1u << (2 * k))) ? fmaxf(d.x * ab0.x, d.y * ab0.y) : 0.f;
      const float e01 = (Mb0 & (2u << (2 * k))) ? fmaxf(d.z * ab0.x, d.w * ab0.y) : 0.f;
      const float e10 = (Mb1 & (1u << (2 * k))) ? fmaxf(d.x * ab1.x, d.y * ab1.y) : 0.f;
      const float e11 = (Mb1 & (2u << (2 * k))) ? fmaxf(d.z * ab1.x, d.w * ab1.y) : 0.f;
      pk0[k] = pack2bf(e00, e01);
      pk1[k] = pack2bf(e10, e11);
    }
    const b16x8 E0 = __builtin_bit_cast(b16x8, pk0);
    const b16x8 E1 = __builtin_bit_cast(b16x8, pk1);
#pragma unroll
    for (int g = 0; g < 4; ++g) {
      acc0[g] = __builtin_amdgcn_mfma_f32_16x16x32_bf16(E0, bF[g], acc0[g], 0, 0, 0);
      acc1[g] = __builtin_amdgcn_mfma_f32_16x16x32_bf16(E1, bF[g], acc1[g], 0, 0, 0);
    }
    lacc0 = __builtin_amdgcn_mfma_f32_16x16x32_bf16(E0, ones, lacc0, 0, 0, 0);
    lacc1 = __builtin_amdgcn_mfma_f32_16x16x32_bf16(E1, ones, lacc1, 0, 0, 0);
  }

#pragma unroll
  for (int g = 0; g < 4; ++g)
#pragma unroll
    for (int r = 0; r < 4; ++r) {
      const int col = h * CH + g * 16 + n;
      pacc[((size_t)slice * NN + ib + q * 4 + r) * C + col] = (_Float16)acc0[g][r];
      pacc[((size_t)slice * NN + ib + 16 + q * 4 + r) * C + col] = (_Float16)acc1[g][r];
    }
  if (n == 0) {
#pragma unroll
    for (int r = 0; r < 4; ++r) {
      lpart[((size_t)slice * NN + ib + q * 4 + r) * NH + h] = lacc0[r];
      lpart[((size_t)slice * NN + ib + 16 + q * 4 + r) * NH + h] = lacc1[r];
    }
  }
}

// ---------------- Kernel 3: combine j-slices, divide (vectorized: f16x2 loads)
__global__ __launch_bounds__(256) void k_final(
    const _Float16* __restrict__ pacc, const float* __restrict__ lpart,
    float* __restrict__ out) {
  const int t = threadIdx.x;
  const int row = blockIdx.x * 2 + (t >> 7);
  const int tc = t & 127;
  const int c2 = tc * 2;
  const int h = tc >> 5;
  float l = 0.f, sa0 = 0.f, sa1 = 0.f;
#pragma unroll
  for (int sp = 0; sp < JSPLIT; ++sp) {
    l += lpart[((size_t)sp * NN + row) * NH + h];
    const f16x2 v = *(const f16x2*)(pacc + ((size_t)sp * NN + row) * C + c2);
    sa0 += (float)v[0];
    sa1 += (float)v[1];
  }
  const float rl = 1.0f / l;
  *(float2*)(out + (size_t)row * C + c2) = make_float2(sa0 * rl, sa1 * rl);
}

extern "C" void kernel_launch(void* const* d_in, const int* in_sizes, int n_in,
                              void* d_out, int out_size, void* d_ws, size_t ws_size,
                              hipStream_t stream) {
  const float* nf   = (const float*)d_in[0];
  const int* adj    = (const int*)d_in[1];
  const float* W    = (const float*)d_in[2];
  const float* bias = (const float*)d_in[3];
  const float* av   = (const float*)d_in[4];
  float* out = (float*)d_out;

  char* ws = (char*)d_ws;
  unsigned char* packed  = (unsigned char*)ws;                              // 2 MB
  unsigned short* Xbf    = (unsigned short*)(ws + (2u << 20));              // 2 MB
  unsigned short* WT     = (unsigned short*)(ws + (4u << 20));              // 128 KB
  unsigned short* F      = (unsigned short*)(ws + (4u << 20) + (256u << 10)); // 2 MB
  float2* srcAB = (float2*)(ws + (6u << 20) + (256u << 10));                // 128 KB
  float2* EdT2  = (float2*)(ws + (6u << 20) + (384u << 10));                // 128 KB
  float* lpart  = (float*)(ws + (6u << 20) + (512u << 10));                 // 1 MB
  _Float16* pacc = (_Float16*)(ws + (8u << 20));                            // 32 MB

  k_prep<<<1280, 256, 0, stream>>>(nf, W, Xbf, WT);
  k_feats<<<8448, 256, 0, stream>>>(Xbf, WT, bias, av, adj, packed, F, srcAB, EdT2);
  k_attn<<<1024, 512, 0, stream>>>(packed, F, srcAB, EdT2, pacc, lpart);
  k_final<<<NN / 2, 256, 0, stream>>>(pacc, lpart, out);
}

// Round 8
// 142.667 us; speedup vs baseline: 1.0361x; 1.0361x over previous
//
#include <hip/hip_runtime.h>

#define NN 4096
#define C 256
#define NH 4
#define CH 64
#define JSPLIT 16
#define JSLICE (NN / JSPLIT)     // 256
#define NJT (JSLICE / 32)        // 8

typedef float f32x4 __attribute__((ext_vector_type(4)));
typedef __bf16 b16x8 __attribute__((ext_vector_type(8)));
typedef unsigned short u16x8 __attribute__((ext_vector_type(8)));
typedef unsigned int u32x4 __attribute__((ext_vector_type(4)));
typedef _Float16 f16x2 __attribute__((ext_vector_type(2)));

__device__ inline float fast_exp2(float x) {
#if __has_builtin(__builtin_amdgcn_exp2f)
  return __builtin_amdgcn_exp2f(x);
#else
  return exp2f(x);
#endif
}

// pack two f32 -> (bf16(f0) | bf16(f1)<<16), round-half-up via +0x8000, v_perm pack
__device__ inline unsigned pack2bf(float f0, float f1) {
  unsigned u0 = __float_as_uint(f0) + 0x8000u;
  unsigned u1 = __float_as_uint(f1) + 0x8000u;
  return __builtin_amdgcn_perm(u1, u0, 0x07060302u);
}

// single-instruction f32 pair -> packed bf16 (lo = f0, hi = f1), RNE
__device__ inline unsigned cvtpk(float f0, float f1) {
  unsigned r;
  asm("v_cvt_pk_bf16_f32 %0, %1, %2" : "=v"(r) : "v"(f0), "v"(f1));
  return r;
}

// ---------------- Kernel 0: prep — X->bf16, W->bf16 transposed (small, ~2us)
__global__ __launch_bounds__(256) void k_prep(
    const float* __restrict__ X, const float* __restrict__ W,
    unsigned short* __restrict__ Xbf, unsigned short* __restrict__ WT) {
  const int b = blockIdx.x, t = threadIdx.x;
  if (b < 1024) {
    const int idx = b * 256 + t;
    const float4 v = ((const float4*)X)[idx];
    uint2 st;
    st.x = pack2bf(v.x, v.y);
    st.y = pack2bf(v.z, v.w);
    ((uint2*)Xbf)[idx] = st;
  } else {
    const int c = b - 1024;
    const float w = W[(size_t)t * C + c];
    WT[(size_t)c * C + t] = (unsigned short)((__float_as_uint(w) + 0x8000u) >> 16);
  }
}

// ---------------- Kernel 1: feats GEMM (blocks 0..255) MERGED with adj bit-packing
// (blocks 256..8447) so the 64MB adj stream overlaps the 255-idle-CU GEMM.
__global__ __launch_bounds__(256) void k_feats(
    const unsigned short* __restrict__ Xbf, const unsigned short* __restrict__ WT,
    const float* __restrict__ bias, const float* __restrict__ av,
    const int* __restrict__ adj, unsigned char* __restrict__ packed,
    unsigned short* __restrict__ F, float2* __restrict__ srcAB,
    float* __restrict__ Ed) {
  if (blockIdx.x >= 256) {
    const int idx = (blockIdx.x - 256) * 256 + threadIdx.x;
    const int4 a0 = *(const int4*)(adj + (size_t)idx * 8);
    const int4 a1 = *(const int4*)(adj + (size_t)idx * 8 + 4);
    unsigned m = 0;
    m |= (a0.x != 0) ? 1u : 0u;   m |= (a0.y != 0) ? 2u : 0u;
    m |= (a0.z != 0) ? 4u : 0u;   m |= (a0.w != 0) ? 8u : 0u;
    m |= (a1.x != 0) ? 16u : 0u;  m |= (a1.y != 0) ? 32u : 0u;
    m |= (a1.z != 0) ? 64u : 0u;  m |= (a1.w != 0) ? 128u : 0u;
    packed[idx] = (unsigned char)m;
    return;
  }
  const int i0 = blockIdx.x * 16;
  const int h = threadIdx.x >> 6;
  const int lane = threadIdx.x & 63;
  const int q = lane >> 4, n = lane & 15;
  const int c0 = h * CH;
  const float LOG2E = 1.4426950408889634f;

  const f32x4 zero = {0.f, 0.f, 0.f, 0.f};
  f32x4 acc[4];
#pragma unroll
  for (int g = 0; g < 4; ++g) acc[g] = zero;

  const unsigned short* ap = Xbf + (size_t)(i0 + n) * C + q * 8;
#pragma unroll
  for (int kt = 0; kt < 8; ++kt) {
    const b16x8 aF = __builtin_bit_cast(b16x8, *(const u16x8*)(ap + kt * 32));
#pragma unroll
    for (int g = 0; g < 4; ++g) {
      const b16x8 bF = __builtin_bit_cast(b16x8,
          *(const u16x8*)(WT + (size_t)(c0 + g * 16 + n) * C + kt * 32 + q * 8));
      acc[g] = __builtin_amdgcn_mfma_f32_16x16x32_bf16(aF, bF, acc[g], 0, 0, 0);
    }
  }

  float fb[4][4], asv[4], adv[4];
#pragma unroll
  for (int g = 0; g < 4; ++g) {
    const float bs = bias[c0 + g * 16 + n];
    asv[g] = av[h * 128 + g * 16 + n];
    adv[g] = av[h * 128 + 64 + g * 16 + n];
#pragma unroll
    for (int r = 0; r < 4; ++r) fb[g][r] = acc[g][r] + bs;
  }
  const int jt = i0 >> 5, half = (i0 >> 4) & 1;
  const int qp = half * 2 + (q >> 1);
#pragma unroll
  for (int g = 0; g < 4; ++g) {
    uint2 st;
    st.x = pack2bf(fb[g][0], fb[g][1]);
    st.y = pack2bf(fb[g][2], fb[g][3]);
    *(uint2*)(F + ((size_t)((jt * NH + h) * 4 + g)) * 512 + (qp * 16 + n) * 8 + 4 * (q & 1)) = st;
  }
  // factored softmax: e_ij = max(e^{d_j}*A_i, e^{.2d_j}*B_i); A,B row-stable-scaled.
  // Ed is SoA: plane 0 = e^{d}, plane 1 = e^{.2d} (enables packed f32 math in k_attn)
#pragma unroll
  for (int r = 0; r < 4; ++r) {
    float p = 0.f, d = 0.f;
#pragma unroll
    for (int g = 0; g < 4; ++g) {
      p = fmaf(fb[g][r], asv[g], p);
      d = fmaf(fb[g][r], adv[g], d);
    }
#pragma unroll
    for (int m = 1; m < 16; m <<= 1) {
      p += __shfl_xor(p, m);
      d += __shfl_xor(d, m);
    }
    if (n == 0) {
      const int row = i0 + q * 4 + r;
      const float dL = d * LOG2E;
      Ed[(size_t)h * NN + row] = fast_exp2(dL);
      Ed[(size_t)NH * NN + (size_t)h * NN + row] = fast_exp2(0.2f * dL);
      const float x = p + 16.0f;
      const float m2 = fmaxf(x, 0.2f * x) * LOG2E;
      srcAB[(size_t)row * NH + h] = make_float2(
          fast_exp2(fmaf(p, LOG2E, -m2)),
          fast_exp2(fmaf(0.2f * p, LOG2E, -m2)));
    }
  }
}

// ---------------- Kernel 2: masked-softmax attention + PV via MFMA (flat, r2-style)
// wave = 32 rows x 1 head; grid (slice, iblock) -> natural XCD round-robin.
// Inner loop: zero transcendentals; SoA Ed planes -> f32x4 ops (v_pk_mul_f32);
// v_cvt_pk_bf16_f32 packs 2 f32 in ONE inst (was 3: 2 add + perm).
// LDS staging removed: round-6 proved F is L2-resident (FETCH 5.7MB) and the
// per-jt barrier drain cost more than the latency it hid (45us vs ~30 flat).
// launch_bounds stays (256,4): min-waves 8 would cap 64 VGPR and spill (round 4).
__global__ __launch_bounds__(256, 4) void k_attn(
    const unsigned char* __restrict__ packed,
    const unsigned short* __restrict__ F,
    const float2* __restrict__ srcAB, const float* __restrict__ Ed,
    _Float16* __restrict__ pacc, float* __restrict__ lpart) {
  const int slice = blockIdx.x;
  const int i0 = blockIdx.y * 32;
  const int h = threadIdx.x >> 6;
  const int lane = threadIdx.x & 63;
  const int q = lane >> 4, n = lane & 15;
  const int jbase = slice * JSLICE;

  const int r0 = i0 + n, r1 = i0 + 16 + n;
  const float2 ab0 = srcAB[(size_t)r0 * NH + h];
  const float2 ab1 = srcAB[(size_t)r1 * NH + h];

  const f32x4 zero = {0.f, 0.f, 0.f, 0.f};
  f32x4 acc0[4], acc1[4], lacc0 = zero, lacc1 = zero;
#pragma unroll
  for (int g = 0; g < 4; ++g) { acc0[g] = zero; acc1[g] = zero; }

  u16x8 ou;
#pragma unroll
  for (int jj = 0; jj < 8; ++jj) ou[jj] = 0x3F80;
  const b16x8 ones = __builtin_bit_cast(b16x8, ou);

  // preload slice masks: lane (q,n) holds 8-byte chunk q of rows r0 / r1
  const uint2 m20 = *(const uint2*)(packed + (size_t)r0 * 512 + (jbase >> 3) + q * 8);
  const uint2 m21 = *(const uint2*)(packed + (size_t)r1 * 512 + (jbase >> 3) + q * 8);

  const float* pa = Ed + (size_t)h * NN + jbase;            // e^d plane
  const float* pb = pa + (size_t)NH * NN;                   // e^{.2d} plane
  const unsigned short* fp = F + ((size_t)((jbase >> 5) * NH + h) * 4) * 512 + lane * 8;

#pragma unroll
  for (int a = 0; a < 4; ++a) {
#pragma unroll
    for (int b = 0; b < 2; ++b) {
      const int jt = a * 2 + b;
      // coalesced B-fragment loads: 4 x 1KB sequential (L2-resident)
      b16x8 bF[4];
#pragma unroll
      for (int g = 0; g < 4; ++g)
        bF[g] = __builtin_bit_cast(b16x8,
            *(const u16x8*)(fp + (size_t)(jt * NH * 4 + g) * 512));

      // masks via shfl from preloaded chunks: byte (a*8 + b*4 + q), src lane a*16+n
      const int w0 = b ? (int)m20.y : (int)m20.x;
      const int w1 = b ? (int)m21.y : (int)m21.x;
      const unsigned Mb0 = (unsigned(__shfl(w0, a * 16 + n)) >> (q * 8)) & 0xffu;
      const unsigned Mb1 = (unsigned(__shfl(w1, a * 16 + n)) >> (q * 8)) & 0xffu;

      // SoA exp loads: lane's 8 j's from each plane (broadcast, L2-hit)
      const int off = jt * 32 + q * 8;
      const f32x4 eA[2] = { *(const f32x4*)(pa + off), *(const f32x4*)(pa + off + 4) };
      const f32x4 eB[2] = { *(const f32x4*)(pb + off), *(const f32x4*)(pb + off + 4) };

      u32x4 pk0, pk1;
#pragma unroll
      for (int hf = 0; hf < 2; ++hf) {
        const f32x4 xa0 = eA[hf] * ab0.x;   // v_pk_mul_f32 pairs
        const f32x4 xb0 = eB[hf] * ab0.y;
        const f32x4 xa1 = eA[hf] * ab1.x;
        const f32x4 xb1 = eB[hf] * ab1.y;
        float e0[4], e1[4];
#pragma unroll
        for (int t2 = 0; t2 < 4; ++t2) {
          const unsigned bit = 1u << (hf * 4 + t2);
          e0[t2] = (Mb0 & bit) ? fmaxf(xa0[t2], xb0[t2]) : 0.f;
          e1[t2] = (Mb1 & bit) ? fmaxf(xa1[t2], xb1[t2]) : 0.f;
        }
        pk0[hf * 2]     = cvtpk(e0[0], e0[1]);
        pk0[hf * 2 + 1] = cvtpk(e0[2], e0[3]);
        pk1[hf * 2]     = cvtpk(e1[0], e1[1]);
        pk1[hf * 2 + 1] = cvtpk(e1[2], e1[3]);
      }
      const b16x8 E0 = __builtin_bit_cast(b16x8, pk0);
      const b16x8 E1 = __builtin_bit_cast(b16x8, pk1);
#pragma unroll
      for (int g = 0; g < 4; ++g) {
        acc0[g] = __builtin_amdgcn_mfma_f32_16x16x32_bf16(E0, bF[g], acc0[g], 0, 0, 0);
        acc1[g] = __builtin_amdgcn_mfma_f32_16x16x32_bf16(E1, bF[g], acc1[g], 0, 0, 0);
      }
      lacc0 = __builtin_amdgcn_mfma_f32_16x16x32_bf16(E0, ones, lacc0, 0, 0, 0);
      lacc1 = __builtin_amdgcn_mfma_f32_16x16x32_bf16(E1, ones, lacc1, 0, 0, 0);
    }
  }

#pragma unroll
  for (int g = 0; g < 4; ++g)
#pragma unroll
    for (int r = 0; r < 4; ++r) {
      const int col = h * CH + g * 16 + n;
      pacc[((size_t)slice * NN + i0 + q * 4 + r) * C + col] = (_Float16)acc0[g][r];
      pacc[((size_t)slice * NN + i0 + 16 + q * 4 + r) * C + col] = (_Float16)acc1[g][r];
    }
  if (n == 0) {
#pragma unroll
    for (int r = 0; r < 4; ++r) {
      lpart[((size_t)slice * NN + i0 + q * 4 + r) * NH + h] = lacc0[r];
      lpart[((size_t)slice * NN + i0 + 16 + q * 4 + r) * NH + h] = lacc1[r];
    }
  }
}

// ---------------- Kernel 3: combine j-slices, divide (vectorized: f16x2 loads)
__global__ __launch_bounds__(256) void k_final(
    const _Float16* __restrict__ pacc, const float* __restrict__ lpart,
    float* __restrict__ out) {
  const int t = threadIdx.x;
  const int row = blockIdx.x * 2 + (t >> 7);
  const int tc = t & 127;
  const int c2 = tc * 2;
  const int h = tc >> 5;
  float l = 0.f, sa0 = 0.f, sa1 = 0.f;
#pragma unroll
  for (int sp = 0; sp < JSPLIT; ++sp) {
    l += lpart[((size_t)sp * NN + row) * NH + h];
    const f16x2 v = *(const f16x2*)(pacc + ((size_t)sp * NN + row) * C + c2);
    sa0 += (float)v[0];
    sa1 += (float)v[1];
  }
  const float rl = 1.0f / l;
  *(float2*)(out + (size_t)row * C + c2) = make_float2(sa0 * rl, sa1 * rl);
}

extern "C" void kernel_launch(void* const* d_in, const int* in_sizes, int n_in,
                              void* d_out, int out_size, void* d_ws, size_t ws_size,
                              hipStream_t stream) {
  const float* nf   = (const float*)d_in[0];
  const int* adj    = (const int*)d_in[1];
  const float* W    = (const float*)d_in[2];
  const float* bias = (const float*)d_in[3];
  const float* av   = (const float*)d_in[4];
  float* out = (float*)d_out;

  char* ws = (char*)d_ws;
  unsigned char* packed  = (unsigned char*)ws;                              // 2 MB
  unsigned short* Xbf    = (unsigned short*)(ws + (2u << 20));              // 2 MB
  unsigned short* WT     = (unsigned short*)(ws + (4u << 20));              // 128 KB
  unsigned short* F      = (unsigned short*)(ws + (4u << 20) + (256u << 10)); // 2 MB
  float2* srcAB = (float2*)(ws + (6u << 20) + (256u << 10));                // 128 KB
  float* Ed     = (float*)(ws + (6u << 20) + (384u << 10));                 // 128 KB (2 planes)
  float* lpart  = (float*)(ws + (6u << 20) + (512u << 10));                 // 1 MB
  _Float16* pacc = (_Float16*)(ws + (8u << 20));                            // 32 MB

  k_prep<<<1280, 256, 0, stream>>>(nf, W, Xbf, WT);
  k_feats<<<8448, 256, 0, stream>>>(Xbf, WT, bias, av, adj, packed, F, srcAB, Ed);
  dim3 g2(JSPLIT, NN / 32);
  k_attn<<<g2, 256, 0, stream>>>(packed, F, srcAB, Ed, pacc, lpart);
  k_final<<<NN / 2, 256, 0, stream>>>(pacc, lpart, out);
}

// Round 9
// 142.353 us; speedup vs baseline: 1.0383x; 1.0022x over previous
//
#include <hip/hip_runtime.h>

#define NN 4096
#define C 256
#define NH 4
#define CH 64
#define JSPLIT 16
#define JSLICE (NN / JSPLIT)     // 256
#define NJT (JSLICE / 32)        // 8

typedef float f32x4 __attribute__((ext_vector_type(4)));
typedef __bf16 b16x8 __attribute__((ext_vector_type(8)));
typedef unsigned short u16x8 __attribute__((ext_vector_type(8)));
typedef unsigned int u32x4 __attribute__((ext_vector_type(4)));
typedef _Float16 f16x2 __attribute__((ext_vector_type(2)));

__device__ inline float fast_exp2(float x) {
#if __has_builtin(__builtin_amdgcn_exp2f)
  return __builtin_amdgcn_exp2f(x);
#else
  return exp2f(x);
#endif
}

// pack two f32 -> (bf16(f0) | bf16(f1)<<16), round-half-up via +0x8000, v_perm pack
__device__ inline unsigned pack2bf(float f0, float f1) {
  unsigned u0 = __float_as_uint(f0) + 0x8000u;
  unsigned u1 = __float_as_uint(f1) + 0x8000u;
  return __builtin_amdgcn_perm(u1, u0, 0x07060302u);
}

// single-instruction f32 pair -> packed bf16 (lo = f0, hi = f1), RNE
__device__ inline unsigned cvtpk(float f0, float f1) {
  unsigned r;
  asm("v_cvt_pk_bf16_f32 %0, %1, %2" : "=v"(r) : "v"(f0), "v"(f1));
  return r;
}

// ---------------- Kernel 0: prep — X->bf16, W->bf16 transposed (small, ~2us)
__global__ __launch_bounds__(256) void k_prep(
    const float* __restrict__ X, const float* __restrict__ W,
    unsigned short* __restrict__ Xbf, unsigned short* __restrict__ WT) {
  const int b = blockIdx.x, t = threadIdx.x;
  if (b < 1024) {
    const int idx = b * 256 + t;
    const float4 v = ((const float4*)X)[idx];
    uint2 st;
    st.x = pack2bf(v.x, v.y);
    st.y = pack2bf(v.z, v.w);
    ((uint2*)Xbf)[idx] = st;
  } else {
    const int c = b - 1024;
    const float w = W[(size_t)t * C + c];
    WT[(size_t)c * C + t] = (unsigned short)((__float_as_uint(w) + 0x8000u) >> 16);
  }
}

// ---------------- Kernel 1: feats GEMM (blocks 0..255) MERGED with adj bit-packing
// (blocks 256..8447) so the 64MB adj stream overlaps the 255-idle-CU GEMM.
__global__ __launch_bounds__(256) void k_feats(
    const unsigned short* __restrict__ Xbf, const unsigned short* __restrict__ WT,
    const float* __restrict__ bias, const float* __restrict__ av,
    const int* __restrict__ adj, unsigned char* __restrict__ packed,
    unsigned short* __restrict__ F, float2* __restrict__ srcAB,
    float* __restrict__ Ed) {
  if (blockIdx.x >= 256) {
    const int idx = (blockIdx.x - 256) * 256 + threadIdx.x;
    const int4 a0 = *(const int4*)(adj + (size_t)idx * 8);
    const int4 a1 = *(const int4*)(adj + (size_t)idx * 8 + 4);
    unsigned m = 0;
    m |= (a0.x != 0) ? 1u : 0u;   m |= (a0.y != 0) ? 2u : 0u;
    m |= (a0.z != 0) ? 4u : 0u;   m |= (a0.w != 0) ? 8u : 0u;
    m |= (a1.x != 0) ? 16u : 0u;  m |= (a1.y != 0) ? 32u : 0u;
    m |= (a1.z != 0) ? 64u : 0u;  m |= (a1.w != 0) ? 128u : 0u;
    packed[idx] = (unsigned char)m;
    return;
  }
  const int i0 = blockIdx.x * 16;
  const int h = threadIdx.x >> 6;
  const int lane = threadIdx.x & 63;
  const int q = lane >> 4, n = lane & 15;
  const int c0 = h * CH;
  const float LOG2E = 1.4426950408889634f;

  const f32x4 zero = {0.f, 0.f, 0.f, 0.f};
  f32x4 acc[4];
#pragma unroll
  for (int g = 0; g < 4; ++g) acc[g] = zero;

  const unsigned short* ap = Xbf + (size_t)(i0 + n) * C + q * 8;
#pragma unroll
  for (int kt = 0; kt < 8; ++kt) {
    const b16x8 aF = __builtin_bit_cast(b16x8, *(const u16x8*)(ap + kt * 32));
#pragma unroll
    for (int g = 0; g < 4; ++g) {
      const b16x8 bF = __builtin_bit_cast(b16x8,
          *(const u16x8*)(WT + (size_t)(c0 + g * 16 + n) * C + kt * 32 + q * 8));
      acc[g] = __builtin_amdgcn_mfma_f32_16x16x32_bf16(aF, bF, acc[g], 0, 0, 0);
    }
  }

  float fb[4][4], asv[4], adv[4];
#pragma unroll
  for (int g = 0; g < 4; ++g) {
    const float bs = bias[c0 + g * 16 + n];
    asv[g] = av[h * 128 + g * 16 + n];
    adv[g] = av[h * 128 + 64 + g * 16 + n];
#pragma unroll
    for (int r = 0; r < 4; ++r) fb[g][r] = acc[g][r] + bs;
  }
  const int jt = i0 >> 5, half = (i0 >> 4) & 1;
  const int qp = half * 2 + (q >> 1);
#pragma unroll
  for (int g = 0; g < 4; ++g) {
    uint2 st;
    st.x = pack2bf(fb[g][0], fb[g][1]);
    st.y = pack2bf(fb[g][2], fb[g][3]);
    *(uint2*)(F + ((size_t)((jt * NH + h) * 4 + g)) * 512 + (qp * 16 + n) * 8 + 4 * (q & 1)) = st;
  }
  // factored softmax: e_ij = max(e^{d_j}*A_i, e^{.2d_j}*B_i); A,B row-stable-scaled.
  // Ed is SoA: plane 0 = e^{d}, plane 1 = e^{.2d} (enables packed f32 math in k_attn)
#pragma unroll
  for (int r = 0; r < 4; ++r) {
    float p = 0.f, d = 0.f;
#pragma unroll
    for (int g = 0; g < 4; ++g) {
      p = fmaf(fb[g][r], asv[g], p);
      d = fmaf(fb[g][r], adv[g], d);
    }
#pragma unroll
    for (int m = 1; m < 16; m <<= 1) {
      p += __shfl_xor(p, m);
      d += __shfl_xor(d, m);
    }
    if (n == 0) {
      const int row = i0 + q * 4 + r;
      const float dL = d * LOG2E;
      Ed[(size_t)h * NN + row] = fast_exp2(dL);
      Ed[(size_t)NH * NN + (size_t)h * NN + row] = fast_exp2(0.2f * dL);
      const float x = p + 16.0f;
      const float m2 = fmaxf(x, 0.2f * x) * LOG2E;
      srcAB[(size_t)row * NH + h] = make_float2(
          fast_exp2(fmaf(p, LOG2E, -m2)),
          fast_exp2(fmaf(0.2f * p, LOG2E, -m2)));
    }
  }
}

// ---------------- Kernel 2: masked-softmax attention + PV via MFMA (flat)
// wave = 32 rows x 1 head; grid (slice, iblock) -> natural XCD round-robin.
// Round-8 improvements on top of the trimmed VALU loop:
//  (1) Ed planes staged to LDS ONCE per block (8KB, single barrier — unlike r6's
//      per-jt barrier) -> per-jt exp reads become broadcast LDS reads, cutting
//      4 of 8 per-jt L2 loads off the dependent chain.
//  (2) bF fragments rotate through explicit next-registers: jt+1's loads issue
//      before jt's E-math, so L2 latency hides under ~200cy of independent VALU.
// launch_bounds stays (256,4): min-waves 8 would cap 64 VGPR and spill (round 4).
__global__ __launch_bounds__(256, 4) void k_attn(
    const unsigned char* __restrict__ packed,
    const unsigned short* __restrict__ F,
    const float2* __restrict__ srcAB, const float* __restrict__ Ed,
    _Float16* __restrict__ pacc, float* __restrict__ lpart) {
  __shared__ float sEd[NH * 2 * 256];   // [h][plane][j] = 8 KB

  const int slice = blockIdx.x;
  const int i0 = blockIdx.y * 32;
  const int tid = threadIdx.x;
  const int h = tid >> 6;
  const int lane = tid & 63;
  const int q = lane >> 4, n = lane & 15;
  const int jbase = slice * JSLICE;

  // ---- stage Ed for this slice (all heads, both planes), coalesced, one barrier
  {
    const int hh = tid >> 6;            // 0..3
    const int pl = (tid >> 5) & 1;      // plane
    const int j8 = (tid & 31) * 8;      // 0..248
    const float* gsrc = Ed + (pl ? (size_t)NH * NN : (size_t)0)
                        + (size_t)hh * NN + jbase + j8;
    const float4 v0 = *(const float4*)(gsrc);
    const float4 v1 = *(const float4*)(gsrc + 4);
    *(float4*)(&sEd[hh * 512 + pl * 256 + j8]) = v0;
    *(float4*)(&sEd[hh * 512 + pl * 256 + j8 + 4]) = v1;
  }

  const int r0 = i0 + n, r1 = i0 + 16 + n;
  const float2 ab0 = srcAB[(size_t)r0 * NH + h];
  const float2 ab1 = srcAB[(size_t)r1 * NH + h];

  const f32x4 zero = {0.f, 0.f, 0.f, 0.f};
  f32x4 acc0[4], acc1[4], lacc0 = zero, lacc1 = zero;
#pragma unroll
  for (int g = 0; g < 4; ++g) { acc0[g] = zero; acc1[g] = zero; }

  u16x8 ou;
#pragma unroll
  for (int jj = 0; jj < 8; ++jj) ou[jj] = 0x3F80;
  const b16x8 ones = __builtin_bit_cast(b16x8, ou);

  // preload slice masks: lane (q,n) holds 8-byte chunk q of rows r0 / r1
  const uint2 m20 = *(const uint2*)(packed + (size_t)r0 * 512 + (jbase >> 3) + q * 8);
  const uint2 m21 = *(const uint2*)(packed + (size_t)r1 * 512 + (jbase >> 3) + q * 8);

  const unsigned short* fp = F + ((size_t)((jbase >> 5) * NH + h) * 4) * 512 + lane * 8;
  const float* sB = &sEd[h * 512];

  __syncthreads();   // sEd ready

  // prologue: bF for jt=0
  b16x8 bFn[4];
#pragma unroll
  for (int g = 0; g < 4; ++g)
    bFn[g] = __builtin_bit_cast(b16x8, *(const u16x8*)(fp + (size_t)(0 * NH * 4 + g) * 512));

#pragma unroll
  for (int jt = 0; jt < NJT; ++jt) {
    const b16x8 bF0 = bFn[0], bF1 = bFn[1], bF2 = bFn[2], bF3 = bFn[3];
    if (jt + 1 < NJT) {   // issue next tile's loads before this tile's E-math
#pragma unroll
      for (int g = 0; g < 4; ++g)
        bFn[g] = __builtin_bit_cast(b16x8,
            *(const u16x8*)(fp + (size_t)((jt + 1) * NH * 4 + g) * 512));
    }

    // masks via shfl from preloaded chunks: byte (jt*4 + q), src lane (jt>>1)*16+n
    const int a = jt >> 1, b = jt & 1;
    const int w0 = b ? (int)m20.y : (int)m20.x;
    const int w1 = b ? (int)m21.y : (int)m21.x;
    const unsigned Mb0 = (unsigned(__shfl(w0, a * 16 + n)) >> (q * 8)) & 0xffu;
    const unsigned Mb1 = (unsigned(__shfl(w1, a * 16 + n)) >> (q * 8)) & 0xffu;

    // SoA exp loads from LDS (broadcast within 16-lane groups, conflict-free)
    const int off = jt * 32 + q * 8;
    const f32x4 eA[2] = { *(const f32x4*)(sB + off), *(const f32x4*)(sB + off + 4) };
    const f32x4 eB[2] = { *(const f32x4*)(sB + 256 + off), *(const f32x4*)(sB + 256 + off + 4) };

    u32x4 pk0, pk1;
#pragma unroll
    for (int hf = 0; hf < 2; ++hf) {
      const f32x4 xa0 = eA[hf] * ab0.x;   // v_pk_mul_f32 pairs
      const f32x4 xb0 = eB[hf] * ab0.y;
      const f32x4 xa1 = eA[hf] * ab1.x;
      const f32x4 xb1 = eB[hf] * ab1.y;
      float e0[4], e1[4];
#pragma unroll
      for (int t2 = 0; t2 < 4; ++t2) {
        const unsigned bit = 1u << (hf * 4 + t2);
        e0[t2] = (Mb0 & bit) ? fmaxf(xa0[t2], xb0[t2]) : 0.f;
        e1[t2] = (Mb1 & bit) ? fmaxf(xa1[t2], xb1[t2]) : 0.f;
      }
      pk0[hf * 2]     = cvtpk(e0[0], e0[1]);
      pk0[hf * 2 + 1] = cvtpk(e0[2], e0[3]);
      pk1[hf * 2]     = cvtpk(e1[0], e1[1]);
      pk1[hf * 2 + 1] = cvtpk(e1[2], e1[3]);
    }
    const b16x8 E0 = __builtin_bit_cast(b16x8, pk0);
    const b16x8 E1 = __builtin_bit_cast(b16x8, pk1);
    acc0[0] = __builtin_amdgcn_mfma_f32_16x16x32_bf16(E0, bF0, acc0[0], 0, 0, 0);
    acc1[0] = __builtin_amdgcn_mfma_f32_16x16x32_bf16(E1, bF0, acc1[0], 0, 0, 0);
    acc0[1] = __builtin_amdgcn_mfma_f32_16x16x32_bf16(E0, bF1, acc0[1], 0, 0, 0);
    acc1[1] = __builtin_amdgcn_mfma_f32_16x16x32_bf16(E1, bF1, acc1[1], 0, 0, 0);
    acc0[2] = __builtin_amdgcn_mfma_f32_16x16x32_bf16(E0, bF2, acc0[2], 0, 0, 0);
    acc1[2] = __builtin_amdgcn_mfma_f32_16x16x32_bf16(E1, bF2, acc1[2], 0, 0, 0);
    acc0[3] = __builtin_amdgcn_mfma_f32_16x16x32_bf16(E0, bF3, acc0[3], 0, 0, 0);
    acc1[3] = __builtin_amdgcn_mfma_f32_16x16x32_bf16(E1, bF3, acc1[3], 0, 0, 0);
    lacc0 = __builtin_amdgcn_mfma_f32_16x16x32_bf16(E0, ones, lacc0, 0, 0, 0);
    lacc1 = __builtin_amdgcn_mfma_f32_16x16x32_bf16(E1, ones, lacc1, 0, 0, 0);
  }

#pragma unroll
  for (int g = 0; g < 4; ++g)
#pragma unroll
    for (int r = 0; r < 4; ++r) {
      const int col = h * CH + g * 16 + n;
      pacc[((size_t)slice * NN + i0 + q * 4 + r) * C + col] = (_Float16)acc0[g][r];
      pacc[((size_t)slice * NN + i0 + 16 + q * 4 + r) * C + col] = (_Float16)acc1[g][r];
    }
  if (n == 0) {
#pragma unroll
    for (int r = 0; r < 4; ++r) {
      lpart[((size_t)slice * NN + i0 + q * 4 + r) * NH + h] = lacc0[r];
      lpart[((size_t)slice * NN + i0 + 16 + q * 4 + r) * NH + h] = lacc1[r];
    }
  }
}

// ---------------- Kernel 3: combine j-slices, divide (vectorized: f16x2 loads)
__global__ __launch_bounds__(256) void k_final(
    const _Float16* __restrict__ pacc, const float* __restrict__ lpart,
    float* __restrict__ out) {
  const int t = threadIdx.x;
  const int row = blockIdx.x * 2 + (t >> 7);
  const int tc = t & 127;
  const int c2 = tc * 2;
  const int h = tc >> 5;
  float l = 0.f, sa0 = 0.f, sa1 = 0.f;
#pragma unroll
  for (int sp = 0; sp < JSPLIT; ++sp) {
    l += lpart[((size_t)sp * NN + row) * NH + h];
    const f16x2 v = *(const f16x2*)(pacc + ((size_t)sp * NN + row) * C + c2);
    sa0 += (float)v[0];
    sa1 += (float)v[1];
  }
  const float rl = 1.0f / l;
  *(float2*)(out + (size_t)row * C + c2) = make_float2(sa0 * rl, sa1 * rl);
}

extern "C" void kernel_launch(void* const* d_in, const int* in_sizes, int n_in,
                              void* d_out, int out_size, void* d_ws, size_t ws_size,
                              hipStream_t stream) {
  const float* nf   = (const float*)d_in[0];
  const int* adj    = (const int*)d_in[1];
  const float* W    = (const float*)d_in[2];
  const float* bias = (const float*)d_in[3];
  const float* av   = (const float*)d_in[4];
  float* out = (float*)d_out;

  char* ws = (char*)d_ws;
  unsigned char* packed  = (unsigned char*)ws;                              // 2 MB
  unsigned short* Xbf    = (unsigned short*)(ws + (2u << 20));              // 2 MB
  unsigned short* WT     = (unsigned short*)(ws + (4u << 20));              // 128 KB
  unsigned short* F      = (unsigned short*)(ws + (4u << 20) + (256u << 10)); // 2 MB
  float2* srcAB = (float2*)(ws + (6u << 20) + (256u << 10));                // 128 KB
  float* Ed     = (float*)(ws + (6u << 20) + (384u << 10));                 // 128 KB (2 planes)
  float* lpart  = (float*)(ws + (6u << 20) + (512u << 10));                 // 1 MB
  _Float16* pacc = (_Float16*)(ws + (8u << 20));                            // 32 MB

  k_prep<<<1280, 256, 0, stream>>>(nf, W, Xbf, WT);
  k_feats<<<8448, 256, 0, stream>>>(Xbf, WT, bias, av, adj, packed, F, srcAB, Ed);
  dim3 g2(JSPLIT, NN / 32);
  k_attn<<<g2, 256, 0, stream>>>(packed, F, srcAB, Ed, pacc, lpart);
  k_final<<<NN / 2, 256, 0, stream>>>(pacc, lpart, out);
}

// Round 10
// 140.802 us; speedup vs baseline: 1.0498x; 1.0110x over previous
//
#include <hip/hip_runtime.h>

#define NN 4096
#define C 256
#define NH 4
#define CH 64
#define JSPLIT 8
#define JSLICE (NN / JSPLIT)     // 512
#define NJT (JSLICE / 32)        // 16

typedef float f32x4 __attribute__((ext_vector_type(4)));
typedef __bf16 b16x8 __attribute__((ext_vector_type(8)));
typedef unsigned short u16x8 __attribute__((ext_vector_type(8)));
typedef unsigned int u32x4 __attribute__((ext_vector_type(4)));
typedef _Float16 f16x2 __attribute__((ext_vector_type(2)));

__device__ inline float fast_exp2(float x) {
#if __has_builtin(__builtin_amdgcn_exp2f)
  return __builtin_amdgcn_exp2f(x);
#else
  return exp2f(x);
#endif
}

// pack two f32 -> (bf16(f0) | bf16(f1)<<16), round-half-up via +0x8000, v_perm pack
__device__ inline unsigned pack2bf(float f0, float f1) {
  unsigned u0 = __float_as_uint(f0) + 0x8000u;
  unsigned u1 = __float_as_uint(f1) + 0x8000u;
  return __builtin_amdgcn_perm(u1, u0, 0x07060302u);
}

// single-instruction f32 pair -> packed bf16 (lo = f0, hi = f1), RNE
__device__ inline unsigned cvtpk(float f0, float f1) {
  unsigned r;
  asm("v_cvt_pk_bf16_f32 %0, %1, %2" : "=v"(r) : "v"(f0), "v"(f1));
  return r;
}

// ---------------- Kernel 0: prep — X->bf16, W->bf16 transposed (small, ~2us)
__global__ __launch_bounds__(256) void k_prep(
    const float* __restrict__ X, const float* __restrict__ W,
    unsigned short* __restrict__ Xbf, unsigned short* __restrict__ WT) {
  const int b = blockIdx.x, t = threadIdx.x;
  if (b < 1024) {
    const int idx = b * 256 + t;
    const float4 v = ((const float4*)X)[idx];
    uint2 st;
    st.x = pack2bf(v.x, v.y);
    st.y = pack2bf(v.z, v.w);
    ((uint2*)Xbf)[idx] = st;
  } else {
    const int c = b - 1024;
    const float w = W[(size_t)t * C + c];
    WT[(size_t)c * C + t] = (unsigned short)((__float_as_uint(w) + 0x8000u) >> 16);
  }
}

// ---------------- Kernel 1: feats GEMM (blocks 0..255) MERGED with adj bit-packing
// (blocks 256..8447) so the 64MB adj stream overlaps the 255-idle-CU GEMM.
__global__ __launch_bounds__(256) void k_feats(
    const unsigned short* __restrict__ Xbf, const unsigned short* __restrict__ WT,
    const float* __restrict__ bias, const float* __restrict__ av,
    const int* __restrict__ adj, unsigned char* __restrict__ packed,
    unsigned short* __restrict__ F, float2* __restrict__ srcAB,
    float* __restrict__ Ed) {
  if (blockIdx.x >= 256) {
    const int idx = (blockIdx.x - 256) * 256 + threadIdx.x;
    const int4 a0 = *(const int4*)(adj + (size_t)idx * 8);
    const int4 a1 = *(const int4*)(adj + (size_t)idx * 8 + 4);
    unsigned m = 0;
    m |= (a0.x != 0) ? 1u : 0u;   m |= (a0.y != 0) ? 2u : 0u;
    m |= (a0.z != 0) ? 4u : 0u;   m |= (a0.w != 0) ? 8u : 0u;
    m |= (a1.x != 0) ? 16u : 0u;  m |= (a1.y != 0) ? 32u : 0u;
    m |= (a1.z != 0) ? 64u : 0u;  m |= (a1.w != 0) ? 128u : 0u;
    packed[idx] = (unsigned char)m;
    return;
  }
  const int i0 = blockIdx.x * 16;
  const int h = threadIdx.x >> 6;
  const int lane = threadIdx.x & 63;
  const int q = lane >> 4, n = lane & 15;
  const int c0 = h * CH;
  const float LOG2E = 1.4426950408889634f;

  const f32x4 zero = {0.f, 0.f, 0.f, 0.f};
  f32x4 acc[4];
#pragma unroll
  for (int g = 0; g < 4; ++g) acc[g] = zero;

  const unsigned short* ap = Xbf + (size_t)(i0 + n) * C + q * 8;
#pragma unroll
  for (int kt = 0; kt < 8; ++kt) {
    const b16x8 aF = __builtin_bit_cast(b16x8, *(const u16x8*)(ap + kt * 32));
#pragma unroll
    for (int g = 0; g < 4; ++g) {
      const b16x8 bF = __builtin_bit_cast(b16x8,
          *(const u16x8*)(WT + (size_t)(c0 + g * 16 + n) * C + kt * 32 + q * 8));
      acc[g] = __builtin_amdgcn_mfma_f32_16x16x32_bf16(aF, bF, acc[g], 0, 0, 0);
    }
  }

  float fb[4][4], asv[4], adv[4];
#pragma unroll
  for (int g = 0; g < 4; ++g) {
    const float bs = bias[c0 + g * 16 + n];
    asv[g] = av[h * 128 + g * 16 + n];
    adv[g] = av[h * 128 + 64 + g * 16 + n];
#pragma unroll
    for (int r = 0; r < 4; ++r) fb[g][r] = acc[g][r] + bs;
  }
  const int jt = i0 >> 5, half = (i0 >> 4) & 1;
  const int qp = half * 2 + (q >> 1);
#pragma unroll
  for (int g = 0; g < 4; ++g) {
    uint2 st;
    st.x = pack2bf(fb[g][0], fb[g][1]);
    st.y = pack2bf(fb[g][2], fb[g][3]);
    *(uint2*)(F + ((size_t)((jt * NH + h) * 4 + g)) * 512 + (qp * 16 + n) * 8 + 4 * (q & 1)) = st;
  }
  // factored softmax: e_ij = max(e^{d_j}*A_i, e^{.2d_j}*B_i); A,B row-stable-scaled.
  // Ed is SoA: plane 0 = e^{d}, plane 1 = e^{.2d}
#pragma unroll
  for (int r = 0; r < 4; ++r) {
    float p = 0.f, d = 0.f;
#pragma unroll
    for (int g = 0; g < 4; ++g) {
      p = fmaf(fb[g][r], asv[g], p);
      d = fmaf(fb[g][r], adv[g], d);
    }
#pragma unroll
    for (int m = 1; m < 16; m <<= 1) {
      p += __shfl_xor(p, m);
      d += __shfl_xor(d, m);
    }
    if (n == 0) {
      const int row = i0 + q * 4 + r;
      const float dL = d * LOG2E;
      Ed[(size_t)h * NN + row] = fast_exp2(dL);
      Ed[(size_t)NH * NN + (size_t)h * NN + row] = fast_exp2(0.2f * dL);
      const float x = p + 16.0f;
      const float m2 = fmaxf(x, 0.2f * x) * LOG2E;
      srcAB[(size_t)row * NH + h] = make_float2(
          fast_exp2(fmaf(p, LOG2E, -m2)),
          fast_exp2(fmaf(0.2f * p, LOG2E, -m2)));
    }
  }
}

// ---------------- Kernel 2: masked-softmax attention + PV via MFMA
// RESTRUCTURED (r10): wave = 16 rows x 1 head over the FULL 512-j slice (NJT=16);
// block = 16 rows x 4 heads; grid (8, 256) = 2048 blocks = 8/CU (occupancy kept)
// while JSPLIT drops 16->8: pacc round-trip halves (32->16MB written+read) and
// k_final's slice loop halves. Live accumulator state halves (acc[4]+lacc = 20
// regs) so VGPR fits the 64-reg/8-wave budget WITHOUT a launch_bounds cap
// (round 4: declared min-waves-8 spills; this does it by shrinking state).
// slice = blockIdx.x in [0,8) -> one slice per XCD, its 256KB F-slice L2-private.
__global__ __launch_bounds__(256, 4) void k_attn(
    const unsigned char* __restrict__ packed,
    const unsigned short* __restrict__ F,
    const float2* __restrict__ srcAB, const float* __restrict__ Ed,
    _Float16* __restrict__ pacc, float* __restrict__ lpart) {
  __shared__ float sEd[NH * 2 * JSLICE];   // [h][plane][j] = 16 KB

  const int slice = blockIdx.x;
  const int i0 = blockIdx.y * 16;
  const int tid = threadIdx.x;
  const int h = tid >> 6;
  const int lane = tid & 63;
  const int q = lane >> 4, n = lane & 15;
  const int jbase = slice * JSLICE;

  // stage Ed for this slice (all heads, both planes), linear LDS layout:
  // per head 1024 floats; lane writes contiguous float4 -> bandwidth-floor stores
  {
#pragma unroll
    for (int v = 0; v < 4; ++v) {
      const int idx = v * 256 + lane * 4;          // 0..1023 within head
      const int pl = idx >> 9, j = idx & 511;
      const float4 vv = *(const float4*)(Ed + (size_t)pl * NH * NN
                                         + (size_t)h * NN + jbase + j);
      *(float4*)(&sEd[h * 1024 + idx]) = vv;
    }
  }

  const int r0 = i0 + n;
  const float2 ab0 = srcAB[(size_t)r0 * NH + h];

  const f32x4 zero = {0.f, 0.f, 0.f, 0.f};
  f32x4 acc[4], lacc = zero;
#pragma unroll
  for (int g = 0; g < 4; ++g) acc[g] = zero;

  u16x8 ou;
#pragma unroll
  for (int jj = 0; jj < 8; ++jj) ou[jj] = 0x3F80;
  const b16x8 ones = __builtin_bit_cast(b16x8, ou);

  // masks: lane (q,n) holds 16 bytes (slice bytes q*16..q*16+15) of row r0
  const u32x4 m4 = *(const u32x4*)(packed + (size_t)r0 * 512 + (jbase >> 3) + q * 16);

  const float* sB = &sEd[h * 1024];
  const unsigned short* fp = F + ((size_t)((jbase >> 5) * NH + h) * 4) * 512 + lane * 8;

  __syncthreads();   // sEd ready

#pragma unroll
  for (int jt = 0; jt < NJT; ++jt) {
    // mask byte (jt*4+q) of row's 64B slice-mask: word jt&3, held by lane (jt>>2)*16+n
    const unsigned Mb =
        (unsigned(__shfl((int)m4[jt & 3], (jt >> 2) * 16 + n)) >> (q * 8)) & 0xffu;

    // SoA exp loads from LDS (16-lane broadcast groups, conflict-free)
    const int off = jt * 32 + q * 8;
    const f32x4 eA[2] = { *(const f32x4*)(sB + off), *(const f32x4*)(sB + off + 4) };
    const f32x4 eB[2] = { *(const f32x4*)(sB + JSLICE + off),
                          *(const f32x4*)(sB + JSLICE + off + 4) };

    u32x4 pk;
#pragma unroll
    for (int hf = 0; hf < 2; ++hf) {
      const f32x4 xa = eA[hf] * ab0.x;   // v_pk_mul_f32 pairs
      const f32x4 xb = eB[hf] * ab0.y;
      float e[4];
#pragma unroll
      for (int t2 = 0; t2 < 4; ++t2) {
        const unsigned bit = 1u << (hf * 4 + t2);
        e[t2] = (Mb & bit) ? fmaxf(xa[t2], xb[t2]) : 0.f;
      }
      pk[hf * 2]     = cvtpk(e[0], e[1]);
      pk[hf * 2 + 1] = cvtpk(e[2], e[3]);
    }
    const b16x8 E = __builtin_bit_cast(b16x8, pk);
#pragma unroll
    for (int g = 0; g < 4; ++g) {
      const b16x8 bF = __builtin_bit_cast(b16x8,
          *(const u16x8*)(fp + (size_t)(jt * NH * 4 + g) * 512));
      acc[g] = __builtin_amdgcn_mfma_f32_16x16x32_bf16(E, bF, acc[g], 0, 0, 0);
    }
    lacc = __builtin_amdgcn_mfma_f32_16x16x32_bf16(E, ones, lacc, 0, 0, 0);
  }

#pragma unroll
  for (int g = 0; g < 4; ++g)
#pragma unroll
    for (int r = 0; r < 4; ++r) {
      const int col = h * CH + g * 16 + n;
      pacc[((size_t)slice * NN + i0 + q * 4 + r) * C + col] = (_Float16)acc[g][r];
    }
  if (n == 0) {
#pragma unroll
    for (int r = 0; r < 4; ++r)
      lpart[((size_t)slice * NN + i0 + q * 4 + r) * NH + h] = lacc[r];
  }
}

// ---------------- Kernel 3: combine j-slices, divide (vectorized: f16x2 loads)
__global__ __launch_bounds__(256) void k_final(
    const _Float16* __restrict__ pacc, const float* __restrict__ lpart,
    float* __restrict__ out) {
  const int t = threadIdx.x;
  const int row = blockIdx.x * 2 + (t >> 7);
  const int tc = t & 127;
  const int c2 = tc * 2;
  const int h = tc >> 5;
  float l = 0.f, sa0 = 0.f, sa1 = 0.f;
#pragma unroll
  for (int sp = 0; sp < JSPLIT; ++sp) {
    l += lpart[((size_t)sp * NN + row) * NH + h];
    const f16x2 v = *(const f16x2*)(pacc + ((size_t)sp * NN + row) * C + c2);
    sa0 += (float)v[0];
    sa1 += (float)v[1];
  }
  const float rl = 1.0f / l;
  *(float2*)(out + (size_t)row * C + c2) = make_float2(sa0 * rl, sa1 * rl);
}

extern "C" void kernel_launch(void* const* d_in, const int* in_sizes, int n_in,
                              void* d_out, int out_size, void* d_ws, size_t ws_size,
                              hipStream_t stream) {
  const float* nf   = (const float*)d_in[0];
  const int* adj    = (const int*)d_in[1];
  const float* W    = (const float*)d_in[2];
  const float* bias = (const float*)d_in[3];
  const float* av   = (const float*)d_in[4];
  float* out = (float*)d_out;

  char* ws = (char*)d_ws;
  unsigned char* packed  = (unsigned char*)ws;                              // 2 MB
  unsigned short* Xbf    = (unsigned short*)(ws + (2u << 20));              // 2 MB
  unsigned short* WT     = (unsigned short*)(ws + (4u << 20));              // 128 KB
  unsigned short* F      = (unsigned short*)(ws + (4u << 20) + (256u << 10)); // 2 MB
  float2* srcAB = (float2*)(ws + (6u << 20) + (256u << 10));                // 128 KB
  float* Ed     = (float*)(ws + (6u << 20) + (384u << 10));                 // 128 KB (2 planes)
  float* lpart  = (float*)(ws + (6u << 20) + (512u << 10));                 // 512 KB
  _Float16* pacc = (_Float16*)(ws + (8u << 20));                            // 16 MB

  k_prep<<<1280, 256, 0, stream>>>(nf, W, Xbf, WT);
  k_feats<<<8448, 256, 0, stream>>>(Xbf, WT, bias, av, adj, packed, F, srcAB, Ed);
  dim3 g2(JSPLIT, NN / 16);
  k_attn<<<g2, 256, 0, stream>>>(packed, F, srcAB, Ed, pacc, lpart);
  k_final<<<NN / 2, 256, 0, stream>>>(pacc, lpart, out);
}